// Round 1
// baseline (1301.449 us; speedup 1.0000x reference)
//
#include <hip/hip_runtime.h>

#define Kst 256
#define Dd 256
#define Vv 50000
#define Tt 512
#define Bb 256
#define KP1 257
#define MD 512
#define NROWS (KP1*KP1)   // 66049
#define EPSf 1e-5f

#define KT 16             // emission k-rows per block
#define VT 1024           // emission vocab per block
#define NVB 49            // ceil(50000/1024)
#define RT 16             // transition rows per block

// ---------------- K1: emission hidden h = LN(lembs + relu(lembs@em_W.T + b)) ----------------
__global__ __launch_bounds__(256) void k_h(
    const float* __restrict__ lembs, const float* __restrict__ em_W,
    const float* __restrict__ em_bias, const float* __restrict__ em_g,
    const float* __restrict__ em_beta, float* __restrict__ h)
{
    int k = blockIdx.x, d = threadIdx.x;
    __shared__ float lrow[Dd];
    __shared__ float red[256];
    lrow[d] = lembs[k*Dd + d];
    __syncthreads();
    float acc = em_bias[d];
    const float4* w4 = (const float4*)(em_W + (size_t)d*Dd);
    for (int j4 = 0; j4 < Dd/4; ++j4) {
        float4 w = w4[j4];
        acc += w.x*lrow[4*j4] + w.y*lrow[4*j4+1] + w.z*lrow[4*j4+2] + w.w*lrow[4*j4+3];
    }
    float val = lrow[d] + fmaxf(acc, 0.f);
    red[d] = val; __syncthreads();
    for (int s = 128; s > 0; s >>= 1) { if (d < s) red[d] += red[d+s]; __syncthreads(); }
    float mu = red[0] * (1.f/Dd);
    __syncthreads();
    float c = val - mu;
    red[d] = c*c; __syncthreads();
    for (int s = 128; s > 0; s >>= 1) { if (d < s) red[d] += red[d+s]; __syncthreads(); }
    float rstd = rsqrtf(red[0] * (1.f/Dd) + EPSf);
    h[k*Dd + d] = c * rstd * em_g[d] + em_beta[d];
}

// ---------------- K2: P0[i,j] = tlembs[i]@tm_W[j,0:256], P1[i,j] = tlembs[i]@tm_W[j,256:512] ----------------
__global__ __launch_bounds__(256) void k_P(
    const float* __restrict__ tlembs, const float* __restrict__ tm_W,
    float* __restrict__ P0, float* __restrict__ P1)
{
    int i = blockIdx.x;            // 0..256
    int tid = threadIdx.x;
    __shared__ float tl[Dd];
    tl[tid] = tlembs[i*Dd + tid];
    __syncthreads();
    for (int half = 0; half < 2; ++half) {
        int j = tid + half*256;
        float a0 = 0.f, a1 = 0.f;
        const float4* w4 = (const float4*)(tm_W + (size_t)j*MD);
        for (int l4 = 0; l4 < 64; ++l4) {
            float4 w = w4[l4];
            a0 += w.x*tl[4*l4] + w.y*tl[4*l4+1] + w.z*tl[4*l4+2] + w.w*tl[4*l4+3];
        }
        for (int l4 = 64; l4 < 128; ++l4) {
            float4 w = w4[l4];
            int l = 4*l4 - 256;
            a1 += w.x*tl[l] + w.y*tl[l+1] + w.z*tl[l+2] + w.w*tl[l+3];
        }
        P0[(size_t)i*MD + j] = a0;
        P1[(size_t)i*MD + j] = a1;
    }
}

// ---------------- K3: emission logsumexp partials over vocab chunks ----------------
__global__ __launch_bounds__(256) void k_em_part(
    const float* __restrict__ h, const float* __restrict__ dec_W,
    const float* __restrict__ dec_b, float* __restrict__ part)
{
    int vb = blockIdx.x, kg = blockIdx.y;
    int tid = threadIdx.x;
    __shared__ float hs[KT][Dd];
    __shared__ float rmx[256], rsm[256];
    for (int idx = tid; idx < KT*Dd; idx += 256)
        hs[idx/Dd][idx%Dd] = h[(kg*KT + idx/Dd)*Dd + idx%Dd];
    __syncthreads();
    float mx[KT], sm[KT];
    #pragma unroll
    for (int k = 0; k < KT; ++k) { mx[k] = -1e30f; sm[k] = 0.f; }
    for (int vi = 0; vi < VT/256; ++vi) {
        int v = vb*VT + vi*256 + tid;
        if (v < Vv) {
            float acc[KT];
            #pragma unroll
            for (int k = 0; k < KT; ++k) acc[k] = 0.f;
            const float4* w4 = (const float4*)(dec_W + (size_t)v*Dd);
            float bv = dec_b[v];
            for (int l4 = 0; l4 < Dd/4; ++l4) {
                float4 w = w4[l4];
                #pragma unroll
                for (int k = 0; k < KT; ++k) {
                    float4 hv = *(const float4*)&hs[k][4*l4];
                    acc[k] += w.x*hv.x + w.y*hv.y + w.z*hv.z + w.w*hv.w;
                }
            }
            #pragma unroll
            for (int k = 0; k < KT; ++k) {
                float lg = acc[k] + bv;
                if (lg > mx[k]) { sm[k] = sm[k]*__expf(mx[k]-lg) + 1.f; mx[k] = lg; }
                else sm[k] += __expf(lg - mx[k]);
            }
        }
    }
    for (int k = 0; k < KT; ++k) {
        rmx[tid] = mx[k]; rsm[tid] = sm[k];
        __syncthreads();
        for (int s = 128; s > 0; s >>= 1) {
            if (tid < s) {
                float m1 = rmx[tid], m2 = rmx[tid+s], s1 = rsm[tid], s2 = rsm[tid+s];
                float m = fmaxf(m1, m2);
                rsm[tid] = s1*__expf(m1-m) + s2*__expf(m2-m);
                rmx[tid] = m;
            }
            __syncthreads();
        }
        if (tid == 0) {
            part[((size_t)(kg*KT+k)*NVB + vb)*2]   = rmx[0];
            part[((size_t)(kg*KT+k)*NVB + vb)*2+1] = rsm[0];
        }
        __syncthreads();
    }
}

// ---------------- K4: combine partials -> lse_em[k] ----------------
__global__ __launch_bounds__(256) void k_em_comb(
    const float* __restrict__ part, float* __restrict__ lse_em)
{
    int k = threadIdx.x;
    float m = -1e30f, s = 0.f;
    for (int vb = 0; vb < NVB; ++vb) {
        float m2 = part[((size_t)k*NVB+vb)*2], s2 = part[((size_t)k*NVB+vb)*2+1];
        if (m2 > m) { s = s*__expf(m - m2) + s2; m = m2; }
        else          s += s2*__expf(m2 - m);
    }
    lse_em[k] = m + logf(s);
}

// ---------------- K5: transition rows -> lse_t[r] (no transdist materialization) ----------------
__global__ __launch_bounds__(256) void k_trans(
    const float* __restrict__ tlembs, const float* __restrict__ P0,
    const float* __restrict__ P1, const float* __restrict__ tm_bias,
    const float* __restrict__ tn_g, const float* __restrict__ tn_beta,
    const float* __restrict__ td_W, const float* __restrict__ td_b,
    float* __restrict__ lse_t)
{
    int r0 = blockIdx.x * RT;
    int tid = threadIdx.x;
    __shared__ float th[RT][MD+4];     // +4 pad: breaks 512-stride bank aliasing
    __shared__ int ri0[RT], ri1[RT];
    __shared__ float mu_s[RT], rstd_s[RT];
    __shared__ float wred[8];
    if (tid < RT) {
        int r = r0 + tid; if (r > NROWS-1) r = NROWS-1;
        int q = r / KP1;
        ri0[tid] = q; ri1[tid] = r - q*KP1;
    }
    __syncthreads();
    // phase 1: h2 = cat + relu(P0[i0] + P1[i1] + bias)
    for (int idx4 = tid; idx4 < RT*(MD/4); idx4 += 256) {
        int row = idx4 >> 7, j4 = idx4 & 127;
        int i0 = ri0[row], i1 = ri1[row];
        float4 a  = ((const float4*)(P0 + (size_t)i0*MD))[j4];
        float4 bb = ((const float4*)(P1 + (size_t)i1*MD))[j4];
        float4 c  = ((const float4*)tm_bias)[j4];
        float4 cat = (j4 < 64) ? ((const float4*)(tlembs + (size_t)i0*Dd))[j4]
                               : ((const float4*)(tlembs + (size_t)i1*Dd))[j4 - 64];
        float4 v;
        v.x = cat.x + fmaxf(a.x+bb.x+c.x, 0.f);
        v.y = cat.y + fmaxf(a.y+bb.y+c.y, 0.f);
        v.z = cat.z + fmaxf(a.z+bb.z+c.z, 0.f);
        v.w = cat.w + fmaxf(a.w+bb.w+c.w, 0.f);
        *(float4*)&th[row][j4 << 2] = v;
    }
    __syncthreads();
    // LN stats: 16 threads per row, strided
    {
        int row = tid >> 4, l = tid & 15;
        float s = 0.f, ss = 0.f;
        for (int jj = 0; jj < 32; ++jj) {
            float v = th[row][l + (jj << 4)];
            s += v; ss += v*v;
        }
        for (int dd = 8; dd > 0; dd >>= 1) {
            s  += __shfl_down(s, dd, 16);
            ss += __shfl_down(ss, dd, 16);
        }
        if (l == 0) {
            float mu = s * (1.f/MD);
            mu_s[row] = mu;
            rstd_s[row] = rsqrtf(ss*(1.f/MD) - mu*mu + EPSf);
        }
    }
    __syncthreads();
    // normalize in place
    for (int idx4 = tid; idx4 < RT*(MD/4); idx4 += 256) {
        int row = idx4 >> 7, j4 = idx4 & 127; int j = j4 << 2;
        float mu = mu_s[row], rs = rstd_s[row];
        float4 v  = *(const float4*)&th[row][j];
        float4 g  = ((const float4*)tn_g)[j4];
        float4 bt = ((const float4*)tn_beta)[j4];
        v.x = (v.x-mu)*rs*g.x + bt.x;
        v.y = (v.y-mu)*rs*g.y + bt.y;
        v.z = (v.z-mu)*rs*g.z + bt.z;
        v.w = (v.w-mu)*rs*g.w + bt.w;
        *(float4*)&th[row][j] = v;
    }
    __syncthreads();
    // phase 2: logits, thread = column c, 16 row accumulators
    float acc[RT];
    #pragma unroll
    for (int r = 0; r < RT; ++r) acc[r] = 0.f;
    const float4* w4 = (const float4*)(td_W + (size_t)tid*MD);
    for (int l4 = 0; l4 < MD/4; ++l4) {
        float4 w = w4[l4];
        #pragma unroll
        for (int r = 0; r < RT; ++r) {
            float4 tv = *(const float4*)&th[r][l4 << 2];
            acc[r] += w.x*tv.x + w.y*tv.y + w.z*tv.z + w.w*tv.w;
        }
    }
    float bc = td_b[tid];
    int lane = tid & 63, wv = tid >> 6;
    for (int r = 0; r < RT; ++r) {
        float lg = acc[r] + bc;
        float m = lg;
        for (int dd = 32; dd > 0; dd >>= 1) m = fmaxf(m, __shfl_xor(m, dd));
        if (lane == 0) wred[wv] = m;
        __syncthreads();
        m = fmaxf(fmaxf(wred[0], wred[1]), fmaxf(wred[2], wred[3]));
        float e = __expf(lg - m);
        for (int dd = 32; dd > 0; dd >>= 1) e += __shfl_xor(e, dd);
        if (lane == 0) wred[4 + wv] = e;
        __syncthreads();
        if (tid == 0 && r0 + r < NROWS)
            lse_t[r0 + r] = m + logf(wred[4]+wred[5]+wred[6]+wred[7]);
        __syncthreads();
    }
}

// ---------------- K6: per-(t,b) gather, one wave per 64 t's, atomic add into out[b] ----------------
__global__ __launch_bounds__(64) void k_gather(
    const int* __restrict__ x, const int* __restrict__ z,
    const float* __restrict__ h, const float* __restrict__ dec_W,
    const float* __restrict__ dec_b, const float* __restrict__ lse_em,
    const float* __restrict__ tlembs, const float* __restrict__ P0,
    const float* __restrict__ P1, const float* __restrict__ tm_bias,
    const float* __restrict__ tn_g, const float* __restrict__ tn_beta,
    const float* __restrict__ td_W, const float* __restrict__ td_b,
    const float* __restrict__ lse_t, float* __restrict__ out)
{
    int b = blockIdx.x;
    int t = blockIdx.y * 64 + threadIdx.x;
    int zc = z[t*Bb + b];
    int xv = x[t*Bb + b];
    float total;
    {   // emission term: h[zc] . dec_W[xv] + dec_b[xv] - lse_em[zc]
        const float4* hw = (const float4*)(h + (size_t)zc*Dd);
        const float4* dw = (const float4*)(dec_W + (size_t)xv*Dd);
        float acc = 0.f;
        for (int l4 = 0; l4 < Dd/4; ++l4) {
            float4 a = hw[l4], w = dw[l4];
            acc += a.x*w.x + a.y*w.y + a.z*w.z + a.w*w.w;
        }
        total = acc + dec_b[xv] - lse_em[zc];
    }
    {   // transition term: recompute th row from P0/P1, dot with td_W[zc]
        int i0 = (t >= 2) ? z[(t-2)*Bb + b] : Kst;
        int i1 = (t >= 1) ? z[(t-1)*Bb + b] : Kst;
        const float4* p0 = (const float4*)(P0 + (size_t)i0*MD);
        const float4* p1 = (const float4*)(P1 + (size_t)i1*MD);
        const float4* c0 = (const float4*)(tlembs + (size_t)i0*Dd);
        const float4* c1 = (const float4*)(tlembs + (size_t)i1*Dd);
        const float4* bj = (const float4*)tm_bias;
        float s = 0.f, ss = 0.f;
        for (int j4 = 0; j4 < MD/4; ++j4) {
            float4 a = p0[j4], bb = p1[j4], c = bj[j4];
            float4 cat = (j4 < 64) ? c0[j4] : c1[j4-64];
            float h0 = cat.x + fmaxf(a.x+bb.x+c.x, 0.f);
            float h1 = cat.y + fmaxf(a.y+bb.y+c.y, 0.f);
            float h2 = cat.z + fmaxf(a.z+bb.z+c.z, 0.f);
            float h3 = cat.w + fmaxf(a.w+bb.w+c.w, 0.f);
            s  += (h0+h1) + (h2+h3);
            ss += (h0*h0+h1*h1) + (h2*h2+h3*h3);
        }
        float mu = s * (1.f/MD);
        float rstd = rsqrtf(ss*(1.f/MD) - mu*mu + EPSf);
        const float4* wr = (const float4*)(td_W + (size_t)zc*MD);
        const float4* gg = (const float4*)tn_g;
        const float4* be = (const float4*)tn_beta;
        float dt = 0.f;
        for (int j4 = 0; j4 < MD/4; ++j4) {
            float4 a = p0[j4], bb = p1[j4], c = bj[j4];
            float4 cat = (j4 < 64) ? c0[j4] : c1[j4-64];
            float4 g = gg[j4], bt = be[j4], w = wr[j4];
            float h0 = cat.x + fmaxf(a.x+bb.x+c.x, 0.f);
            float h1 = cat.y + fmaxf(a.y+bb.y+c.y, 0.f);
            float h2 = cat.z + fmaxf(a.z+bb.z+c.z, 0.f);
            float h3 = cat.w + fmaxf(a.w+bb.w+c.w, 0.f);
            dt += ((h0-mu)*rstd*g.x + bt.x) * w.x
                + ((h1-mu)*rstd*g.y + bt.y) * w.y
                + ((h2-mu)*rstd*g.z + bt.z) * w.z
                + ((h3-mu)*rstd*g.w + bt.w) * w.w;
        }
        total += dt + td_b[zc] - lse_t[i0*KP1 + i1];
    }
    for (int dd = 32; dd > 0; dd >>= 1) total += __shfl_down(total, dd);
    if (threadIdx.x == 0) atomicAdd(&out[b], total);
}

extern "C" void kernel_launch(void* const* d_in, const int* in_sizes, int n_in,
                              void* d_out, int out_size, void* d_ws, size_t ws_size,
                              hipStream_t stream)
{
    const int*   x       = (const int*)  d_in[0];
    const int*   z       = (const int*)  d_in[1];
    const float* lembs   = (const float*)d_in[2];
    const float* tlembs  = (const float*)d_in[3];
    const float* dec_W   = (const float*)d_in[4];
    const float* dec_b   = (const float*)d_in[5];
    const float* em_W    = (const float*)d_in[6];
    const float* em_bias = (const float*)d_in[7];
    const float* em_g    = (const float*)d_in[8];
    const float* em_beta = (const float*)d_in[9];
    const float* td_W    = (const float*)d_in[10];
    const float* td_b    = (const float*)d_in[11];
    const float* tm_W    = (const float*)d_in[12];
    const float* tm_bias = (const float*)d_in[13];
    const float* tn_g    = (const float*)d_in[14];
    const float* tn_beta = (const float*)d_in[15];
    float* out = (float*)d_out;

    float* ws     = (float*)d_ws;
    float* h      = ws;                    // 65536
    float* P0     = h + 65536;             // 257*512 = 131584
    float* P1     = P0 + 131584;           // 131584
    float* lse_em = P1 + 131584;           // 256
    float* part   = lse_em + 256;          // 256*49*2 = 25088
    float* lse_t  = part + 25088;          // 66049
    // total ~1.66 MB of workspace

    hipMemsetAsync(out, 0, Bb*sizeof(float), stream);
    k_h<<<Kst, 256, 0, stream>>>(lembs, em_W, em_bias, em_g, em_beta, h);
    k_P<<<KP1, 256, 0, stream>>>(tlembs, tm_W, P0, P1);
    k_em_part<<<dim3(NVB, Kst/KT), 256, 0, stream>>>(h, dec_W, dec_b, part);
    k_em_comb<<<1, Kst, 0, stream>>>(part, lse_em);
    k_trans<<<(NROWS + RT - 1)/RT, 256, 0, stream>>>(tlembs, P0, P1, tm_bias,
                                                     tn_g, tn_beta, td_W, td_b, lse_t);
    k_gather<<<dim3(Bb, Tt/64), 64, 0, stream>>>(x, z, h, dec_W, dec_b, lse_em,
                                                 tlembs, P0, P1, tm_bias, tn_g, tn_beta,
                                                 td_W, td_b, lse_t, out);
}

// Round 2
// 838.187 us; speedup vs baseline: 1.5527x; 1.5527x over previous
//
#include <hip/hip_runtime.h>

#define Kst 256
#define Dd 256
#define Vv 50000
#define Tt 512
#define Bb 256
#define KP1 257
#define MD 512
#define NROWS (KP1*KP1)   // 66049
#define EPSf 1e-5f

#define KT 16             // emission k-rows per block
#define VT 1024           // emission vocab per block
#define NVB 49            // ceil(50000/1024)

typedef __attribute__((ext_vector_type(8))) short short8;
typedef __attribute__((ext_vector_type(4))) short short4v;
typedef __attribute__((ext_vector_type(4))) float f32x4;

__device__ __forceinline__ unsigned short f2bf(float f) {
    unsigned u = __builtin_bit_cast(unsigned, f);
    unsigned r = (u + 0x7fffu + ((u >> 16) & 1u)) >> 16;
    return (unsigned short)r;
}

// ---------------- K1: emission hidden h = LN(lembs + relu(lembs@em_W.T + b)) ----------------
__global__ __launch_bounds__(256) void k_h(
    const float* __restrict__ lembs, const float* __restrict__ em_W,
    const float* __restrict__ em_bias, const float* __restrict__ em_g,
    const float* __restrict__ em_beta, float* __restrict__ h)
{
    int k = blockIdx.x, d = threadIdx.x;
    __shared__ float lrow[Dd];
    __shared__ float red[256];
    lrow[d] = lembs[k*Dd + d];
    __syncthreads();
    float acc = em_bias[d];
    const float4* w4 = (const float4*)(em_W + (size_t)d*Dd);
    for (int j4 = 0; j4 < Dd/4; ++j4) {
        float4 w = w4[j4];
        acc += w.x*lrow[4*j4] + w.y*lrow[4*j4+1] + w.z*lrow[4*j4+2] + w.w*lrow[4*j4+3];
    }
    float val = lrow[d] + fmaxf(acc, 0.f);
    red[d] = val; __syncthreads();
    for (int s = 128; s > 0; s >>= 1) { if (d < s) red[d] += red[d+s]; __syncthreads(); }
    float mu = red[0] * (1.f/Dd);
    __syncthreads();
    float c = val - mu;
    red[d] = c*c; __syncthreads();
    for (int s = 128; s > 0; s >>= 1) { if (d < s) red[d] += red[d+s]; __syncthreads(); }
    float rstd = rsqrtf(red[0] * (1.f/Dd) + EPSf);
    h[k*Dd + d] = c * rstd * em_g[d] + em_beta[d];
}

// ---------------- K2: P0[i,j] = tlembs[i]@tm_W[j,0:256], P1[i,j] = tlembs[i]@tm_W[j,256:512] ----------------
__global__ __launch_bounds__(256) void k_P(
    const float* __restrict__ tlembs, const float* __restrict__ tm_W,
    float* __restrict__ P0, float* __restrict__ P1)
{
    int i = blockIdx.x;            // 0..256
    int tid = threadIdx.x;
    __shared__ float tl[Dd];
    tl[tid] = tlembs[i*Dd + tid];
    __syncthreads();
    for (int half = 0; half < 2; ++half) {
        int j = tid + half*256;
        float a0 = 0.f, a1 = 0.f;
        const float4* w4 = (const float4*)(tm_W + (size_t)j*MD);
        for (int l4 = 0; l4 < 64; ++l4) {
            float4 w = w4[l4];
            a0 += w.x*tl[4*l4] + w.y*tl[4*l4+1] + w.z*tl[4*l4+2] + w.w*tl[4*l4+3];
        }
        for (int l4 = 64; l4 < 128; ++l4) {
            float4 w = w4[l4];
            int l = 4*l4 - 256;
            a1 += w.x*tl[l] + w.y*tl[l+1] + w.z*tl[l+2] + w.w*tl[l+3];
        }
        P0[(size_t)i*MD + j] = a0;
        P1[(size_t)i*MD + j] = a1;
    }
}

// ---------------- K2b: td_W -> bf16 copy ----------------
__global__ __launch_bounds__(256) void k_tdw(
    const float* __restrict__ td_W, unsigned short* __restrict__ tdw_bf)
{
    int i = blockIdx.x*256 + threadIdx.x;     // 131072/4 = 32768 threads
    float4 v = ((const float4*)td_W)[i];
    short4v o;
    o.x = (short)f2bf(v.x); o.y = (short)f2bf(v.y);
    o.z = (short)f2bf(v.z); o.w = (short)f2bf(v.w);
    *(short4v*)(tdw_bf + (size_t)i*4) = o;
}

// ---------------- K3: emission logsumexp partials over vocab chunks ----------------
__global__ __launch_bounds__(256) void k_em_part(
    const float* __restrict__ h, const float* __restrict__ dec_W,
    const float* __restrict__ dec_b, float* __restrict__ part)
{
    int vb = blockIdx.x, kg = blockIdx.y;
    int tid = threadIdx.x;
    __shared__ float hs[KT][Dd];
    __shared__ float rmx[256], rsm[256];
    for (int idx = tid; idx < KT*Dd; idx += 256)
        hs[idx/Dd][idx%Dd] = h[(kg*KT + idx/Dd)*Dd + idx%Dd];
    __syncthreads();
    float mx[KT], sm[KT];
    #pragma unroll
    for (int k = 0; k < KT; ++k) { mx[k] = -1e30f; sm[k] = 0.f; }
    for (int vi = 0; vi < VT/256; ++vi) {
        int v = vb*VT + vi*256 + tid;
        if (v < Vv) {
            float acc[KT];
            #pragma unroll
            for (int k = 0; k < KT; ++k) acc[k] = 0.f;
            const float4* w4 = (const float4*)(dec_W + (size_t)v*Dd);
            float bv = dec_b[v];
            for (int l4 = 0; l4 < Dd/4; ++l4) {
                float4 w = w4[l4];
                #pragma unroll
                for (int k = 0; k < KT; ++k) {
                    float4 hv = *(const float4*)&hs[k][4*l4];
                    acc[k] += w.x*hv.x + w.y*hv.y + w.z*hv.z + w.w*hv.w;
                }
            }
            #pragma unroll
            for (int k = 0; k < KT; ++k) {
                float lg = acc[k] + bv;
                if (lg > mx[k]) { sm[k] = sm[k]*__expf(mx[k]-lg) + 1.f; mx[k] = lg; }
                else sm[k] += __expf(lg - mx[k]);
            }
        }
    }
    for (int k = 0; k < KT; ++k) {
        rmx[tid] = mx[k]; rsm[tid] = sm[k];
        __syncthreads();
        for (int s = 128; s > 0; s >>= 1) {
            if (tid < s) {
                float m1 = rmx[tid], m2 = rmx[tid+s], s1 = rsm[tid], s2 = rsm[tid+s];
                float m = fmaxf(m1, m2);
                rsm[tid] = s1*__expf(m1-m) + s2*__expf(m2-m);
                rmx[tid] = m;
            }
            __syncthreads();
        }
        if (tid == 0) {
            part[((size_t)(kg*KT+k)*NVB + vb)*2]   = rmx[0];
            part[((size_t)(kg*KT+k)*NVB + vb)*2+1] = rsm[0];
        }
        __syncthreads();
    }
}

// ---------------- K4: combine partials -> lse_em[k] ----------------
__global__ __launch_bounds__(256) void k_em_comb(
    const float* __restrict__ part, float* __restrict__ lse_em)
{
    int k = threadIdx.x;
    float m = -1e30f, s = 0.f;
    for (int vb = 0; vb < NVB; ++vb) {
        float m2 = part[((size_t)k*NVB+vb)*2], s2 = part[((size_t)k*NVB+vb)*2+1];
        if (m2 > m) { s = s*__expf(m - m2) + s2; m = m2; }
        else          s += s2*__expf(m2 - m);
    }
    lse_em[k] = m + logf(s);
}

// ---------------- K5 (MFMA): transition rows -> lse_t[r] ----------------
// Block = 256 thr (4 waves), 64 rows. Phase A: LN'd th rows -> bf16 LDS.
// Phase B: 64x256x512 GEMM via mfma_f32_16x16x32_bf16, wave w owns cols [w*64,w*64+64).
// Phase C: row-wise logsumexp from C-fragments (col=lane&15, row=(lane>>4)*4+reg).
__global__ __launch_bounds__(256) void k_trans2(
    const float* __restrict__ tlembs, const float* __restrict__ P0,
    const float* __restrict__ P1, const float* __restrict__ tm_bias,
    const float* __restrict__ tn_g, const float* __restrict__ tn_beta,
    const short* __restrict__ tdw_bf, const float* __restrict__ td_b,
    float* __restrict__ lse_t)
{
    __shared__ short th[64][520];          // stride 520 shorts = 1040 B (16B-mult, bank-spread)
    __shared__ float pmax[4][64], psum[4][64], gmax[64];
    int tid = threadIdx.x, lane = tid & 63, wv = tid >> 6;
    int r0 = blockIdx.x * 64;

    // ---- phase A: one wave per row, 16 rows/wave; lane holds j=lane*4 (first half) and 256+j ----
    int j = lane * 4;
    float4 ba  = *(const float4*)(tm_bias + j);
    float4 bb  = *(const float4*)(tm_bias + 256 + j);
    float4 ga  = *(const float4*)(tn_g + j);
    float4 gb  = *(const float4*)(tn_g + 256 + j);
    float4 bta = *(const float4*)(tn_beta + j);
    float4 btb = *(const float4*)(tn_beta + 256 + j);
    for (int i = 0; i < 16; ++i) {
        int row = wv*16 + i;
        int r = r0 + row; if (r >= NROWS) r = NROWS - 1;
        int i0 = r / KP1, i1 = r - i0*KP1;
        float4 p0a = *(const float4*)(P0 + (size_t)i0*MD + j);
        float4 p0b = *(const float4*)(P0 + (size_t)i0*MD + 256 + j);
        float4 p1a = *(const float4*)(P1 + (size_t)i1*MD + j);
        float4 p1b = *(const float4*)(P1 + (size_t)i1*MD + 256 + j);
        float4 ca  = *(const float4*)(tlembs + (size_t)i0*Dd + j);
        float4 cb  = *(const float4*)(tlembs + (size_t)i1*Dd + j);
        float v0 = ca.x + fmaxf(p0a.x + p1a.x + ba.x, 0.f);
        float v1 = ca.y + fmaxf(p0a.y + p1a.y + ba.y, 0.f);
        float v2 = ca.z + fmaxf(p0a.z + p1a.z + ba.z, 0.f);
        float v3 = ca.w + fmaxf(p0a.w + p1a.w + ba.w, 0.f);
        float v4 = cb.x + fmaxf(p0b.x + p1b.x + bb.x, 0.f);
        float v5 = cb.y + fmaxf(p0b.y + p1b.y + bb.y, 0.f);
        float v6 = cb.z + fmaxf(p0b.z + p1b.z + bb.z, 0.f);
        float v7 = cb.w + fmaxf(p0b.w + p1b.w + bb.w, 0.f);
        float s  = ((v0+v1)+(v2+v3)) + ((v4+v5)+(v6+v7));
        float ss = ((v0*v0+v1*v1)+(v2*v2+v3*v3)) + ((v4*v4+v5*v5)+(v6*v6+v7*v7));
        #pragma unroll
        for (int d = 1; d < 64; d <<= 1) {
            s  += __shfl_xor(s, d);
            ss += __shfl_xor(ss, d);
        }
        float mu = s * (1.f/MD);
        float rstd = rsqrtf(ss*(1.f/MD) - mu*mu + EPSf);
        short4v oa, ob;
        oa.x = (short)f2bf((v0-mu)*rstd*ga.x + bta.x);
        oa.y = (short)f2bf((v1-mu)*rstd*ga.y + bta.y);
        oa.z = (short)f2bf((v2-mu)*rstd*ga.z + bta.z);
        oa.w = (short)f2bf((v3-mu)*rstd*ga.w + bta.w);
        ob.x = (short)f2bf((v4-mu)*rstd*gb.x + btb.x);
        ob.y = (short)f2bf((v5-mu)*rstd*gb.y + btb.y);
        ob.z = (short)f2bf((v6-mu)*rstd*gb.z + btb.z);
        ob.w = (short)f2bf((v7-mu)*rstd*gb.w + btb.w);
        *(short4v*)&th[row][j]       = oa;
        *(short4v*)&th[row][256 + j] = ob;
    }
    __syncthreads();

    // ---- phase B: MFMA ----
    int l15 = lane & 15, q = lane >> 4;
    f32x4 acc[4][4];
    #pragma unroll
    for (int rt = 0; rt < 4; ++rt)
        #pragma unroll
        for (int ct = 0; ct < 4; ++ct)
            acc[rt][ct] = (f32x4){0.f, 0.f, 0.f, 0.f};
    const short* tb = tdw_bf + ((size_t)(wv*64 + l15))*MD + q*8;
    #pragma unroll 4
    for (int ks = 0; ks < 16; ++ks) {
        int ko = ks*32 + q*8;
        short8 a0 = *(const short8*)&th[ 0 + l15][ko];
        short8 a1 = *(const short8*)&th[16 + l15][ko];
        short8 a2 = *(const short8*)&th[32 + l15][ko];
        short8 a3 = *(const short8*)&th[48 + l15][ko];
        short8 b0 = *(const short8*)(tb + ks*32);
        short8 b1 = *(const short8*)(tb + 16*MD + ks*32);
        short8 b2 = *(const short8*)(tb + 32*MD + ks*32);
        short8 b3 = *(const short8*)(tb + 48*MD + ks*32);
        acc[0][0] = __builtin_amdgcn_mfma_f32_16x16x32_bf16(a0, b0, acc[0][0], 0,0,0);
        acc[1][0] = __builtin_amdgcn_mfma_f32_16x16x32_bf16(a1, b0, acc[1][0], 0,0,0);
        acc[2][0] = __builtin_amdgcn_mfma_f32_16x16x32_bf16(a2, b0, acc[2][0], 0,0,0);
        acc[3][0] = __builtin_amdgcn_mfma_f32_16x16x32_bf16(a3, b0, acc[3][0], 0,0,0);
        acc[0][1] = __builtin_amdgcn_mfma_f32_16x16x32_bf16(a0, b1, acc[0][1], 0,0,0);
        acc[1][1] = __builtin_amdgcn_mfma_f32_16x16x32_bf16(a1, b1, acc[1][1], 0,0,0);
        acc[2][1] = __builtin_amdgcn_mfma_f32_16x16x32_bf16(a2, b1, acc[2][1], 0,0,0);
        acc[3][1] = __builtin_amdgcn_mfma_f32_16x16x32_bf16(a3, b1, acc[3][1], 0,0,0);
        acc[0][2] = __builtin_amdgcn_mfma_f32_16x16x32_bf16(a0, b2, acc[0][2], 0,0,0);
        acc[1][2] = __builtin_amdgcn_mfma_f32_16x16x32_bf16(a1, b2, acc[1][2], 0,0,0);
        acc[2][2] = __builtin_amdgcn_mfma_f32_16x16x32_bf16(a2, b2, acc[2][2], 0,0,0);
        acc[3][2] = __builtin_amdgcn_mfma_f32_16x16x32_bf16(a3, b2, acc[3][2], 0,0,0);
        acc[0][3] = __builtin_amdgcn_mfma_f32_16x16x32_bf16(a0, b3, acc[0][3], 0,0,0);
        acc[1][3] = __builtin_amdgcn_mfma_f32_16x16x32_bf16(a1, b3, acc[1][3], 0,0,0);
        acc[2][3] = __builtin_amdgcn_mfma_f32_16x16x32_bf16(a2, b3, acc[2][3], 0,0,0);
        acc[3][3] = __builtin_amdgcn_mfma_f32_16x16x32_bf16(a3, b3, acc[3][3], 0,0,0);
    }

    // ---- phase C: add td_b, row-wise logsumexp ----
    float tbc0 = td_b[wv*64 +  0 + l15];
    float tbc1 = td_b[wv*64 + 16 + l15];
    float tbc2 = td_b[wv*64 + 32 + l15];
    float tbc3 = td_b[wv*64 + 48 + l15];
    #pragma unroll
    for (int rt = 0; rt < 4; ++rt) {
        #pragma unroll
        for (int reg = 0; reg < 4; ++reg) {
            acc[rt][0][reg] += tbc0;
            acc[rt][1][reg] += tbc1;
            acc[rt][2][reg] += tbc2;
            acc[rt][3][reg] += tbc3;
        }
    }
    #pragma unroll
    for (int rt = 0; rt < 4; ++rt) {
        #pragma unroll
        for (int reg = 0; reg < 4; ++reg) {
            float m = fmaxf(fmaxf(acc[rt][0][reg], acc[rt][1][reg]),
                            fmaxf(acc[rt][2][reg], acc[rt][3][reg]));
            m = fmaxf(m, __shfl_xor(m, 1));
            m = fmaxf(m, __shfl_xor(m, 2));
            m = fmaxf(m, __shfl_xor(m, 4));
            m = fmaxf(m, __shfl_xor(m, 8));
            if (l15 == 0) pmax[wv][rt*16 + q*4 + reg] = m;
        }
    }
    __syncthreads();
    if (tid < 64)
        gmax[tid] = fmaxf(fmaxf(pmax[0][tid], pmax[1][tid]),
                          fmaxf(pmax[2][tid], pmax[3][tid]));
    __syncthreads();
    #pragma unroll
    for (int rt = 0; rt < 4; ++rt) {
        #pragma unroll
        for (int reg = 0; reg < 4; ++reg) {
            int row = rt*16 + q*4 + reg;
            float g = gmax[row];
            float s = __expf(acc[rt][0][reg] - g) + __expf(acc[rt][1][reg] - g)
                    + __expf(acc[rt][2][reg] - g) + __expf(acc[rt][3][reg] - g);
            s += __shfl_xor(s, 1);
            s += __shfl_xor(s, 2);
            s += __shfl_xor(s, 4);
            s += __shfl_xor(s, 8);
            if (l15 == 0) psum[wv][row] = s;
        }
    }
    __syncthreads();
    if (tid < 64) {
        int r = r0 + tid;
        if (r < NROWS)
            lse_t[r] = gmax[tid] + logf(psum[0][tid] + psum[1][tid] + psum[2][tid] + psum[3][tid]);
    }
}

// ---------------- K6: per-(t,b) gather, one wave per 64 t's, atomic add into out[b] ----------------
__global__ __launch_bounds__(64) void k_gather(
    const int* __restrict__ x, const int* __restrict__ z,
    const float* __restrict__ h, const float* __restrict__ dec_W,
    const float* __restrict__ dec_b, const float* __restrict__ lse_em,
    const float* __restrict__ tlembs, const float* __restrict__ P0,
    const float* __restrict__ P1, const float* __restrict__ tm_bias,
    const float* __restrict__ tn_g, const float* __restrict__ tn_beta,
    const float* __restrict__ td_W, const float* __restrict__ td_b,
    const float* __restrict__ lse_t, float* __restrict__ out)
{
    int b = blockIdx.x;
    int t = blockIdx.y * 64 + threadIdx.x;
    int zc = z[t*Bb + b];
    int xv = x[t*Bb + b];
    float total;
    {   // emission term: h[zc] . dec_W[xv] + dec_b[xv] - lse_em[zc]
        const float4* hw = (const float4*)(h + (size_t)zc*Dd);
        const float4* dw = (const float4*)(dec_W + (size_t)xv*Dd);
        float acc = 0.f;
        for (int l4 = 0; l4 < Dd/4; ++l4) {
            float4 a = hw[l4], w = dw[l4];
            acc += a.x*w.x + a.y*w.y + a.z*w.z + a.w*w.w;
        }
        total = acc + dec_b[xv] - lse_em[zc];
    }
    {   // transition term: recompute th row from P0/P1, dot with td_W[zc]
        int i0 = (t >= 2) ? z[(t-2)*Bb + b] : Kst;
        int i1 = (t >= 1) ? z[(t-1)*Bb + b] : Kst;
        const float4* p0 = (const float4*)(P0 + (size_t)i0*MD);
        const float4* p1 = (const float4*)(P1 + (size_t)i1*MD);
        const float4* c0 = (const float4*)(tlembs + (size_t)i0*Dd);
        const float4* c1 = (const float4*)(tlembs + (size_t)i1*Dd);
        const float4* bj = (const float4*)tm_bias;
        float s = 0.f, ss = 0.f;
        for (int j4 = 0; j4 < MD/4; ++j4) {
            float4 a = p0[j4], bb = p1[j4], c = bj[j4];
            float4 cat = (j4 < 64) ? c0[j4] : c1[j4-64];
            float h0 = cat.x + fmaxf(a.x+bb.x+c.x, 0.f);
            float h1 = cat.y + fmaxf(a.y+bb.y+c.y, 0.f);
            float h2 = cat.z + fmaxf(a.z+bb.z+c.z, 0.f);
            float h3 = cat.w + fmaxf(a.w+bb.w+c.w, 0.f);
            s  += (h0+h1) + (h2+h3);
            ss += (h0*h0+h1*h1) + (h2*h2+h3*h3);
        }
        float mu = s * (1.f/MD);
        float rstd = rsqrtf(ss*(1.f/MD) - mu*mu + EPSf);
        const float4* wr = (const float4*)(td_W + (size_t)zc*MD);
        const float4* gg = (const float4*)tn_g;
        const float4* be = (const float4*)tn_beta;
        float dt = 0.f;
        for (int j4 = 0; j4 < MD/4; ++j4) {
            float4 a = p0[j4], bb = p1[j4], c = bj[j4];
            float4 cat = (j4 < 64) ? c0[j4] : c1[j4-64];
            float4 g = gg[j4], bt = be[j4], w = wr[j4];
            float h0 = cat.x + fmaxf(a.x+bb.x+c.x, 0.f);
            float h1 = cat.y + fmaxf(a.y+bb.y+c.y, 0.f);
            float h2 = cat.z + fmaxf(a.z+bb.z+c.z, 0.f);
            float h3 = cat.w + fmaxf(a.w+bb.w+c.w, 0.f);
            dt += ((h0-mu)*rstd*g.x + bt.x) * w.x
                + ((h1-mu)*rstd*g.y + bt.y) * w.y
                + ((h2-mu)*rstd*g.z + bt.z) * w.z
                + ((h3-mu)*rstd*g.w + bt.w) * w.w;
        }
        total += dt + td_b[zc] - lse_t[i0*KP1 + i1];
    }
    for (int dd = 32; dd > 0; dd >>= 1) total += __shfl_down(total, dd);
    if (threadIdx.x == 0) atomicAdd(&out[b], total);
}

extern "C" void kernel_launch(void* const* d_in, const int* in_sizes, int n_in,
                              void* d_out, int out_size, void* d_ws, size_t ws_size,
                              hipStream_t stream)
{
    const int*   x       = (const int*)  d_in[0];
    const int*   z       = (const int*)  d_in[1];
    const float* lembs   = (const float*)d_in[2];
    const float* tlembs  = (const float*)d_in[3];
    const float* dec_W   = (const float*)d_in[4];
    const float* dec_b   = (const float*)d_in[5];
    const float* em_W    = (const float*)d_in[6];
    const float* em_bias = (const float*)d_in[7];
    const float* em_g    = (const float*)d_in[8];
    const float* em_beta = (const float*)d_in[9];
    const float* td_W    = (const float*)d_in[10];
    const float* td_b    = (const float*)d_in[11];
    const float* tm_W    = (const float*)d_in[12];
    const float* tm_bias = (const float*)d_in[13];
    const float* tn_g    = (const float*)d_in[14];
    const float* tn_beta = (const float*)d_in[15];
    float* out = (float*)d_out;

    float* ws     = (float*)d_ws;
    float* h      = ws;                    // 65536
    float* P0     = h + 65536;             // 257*512 = 131584
    float* P1     = P0 + 131584;           // 131584
    float* lse_em = P1 + 131584;           // 256
    float* part   = lse_em + 256;          // 256*49*2 = 25088
    float* lse_t  = part + 25088;          // 66049
    unsigned short* tdw_bf = (unsigned short*)(lse_t + 66049 + 3); // 256*512 bf16 = 262144 B
    // total ~1.9 MB of workspace

    hipMemsetAsync(out, 0, Bb*sizeof(float), stream);
    k_h<<<Kst, 256, 0, stream>>>(lembs, em_W, em_bias, em_g, em_beta, h);
    k_P<<<KP1, 256, 0, stream>>>(tlembs, tm_W, P0, P1);
    k_tdw<<<128, 256, 0, stream>>>(td_W, tdw_bf);
    k_em_part<<<dim3(NVB, Kst/KT), 256, 0, stream>>>(h, dec_W, dec_b, part);
    k_em_comb<<<1, Kst, 0, stream>>>(part, lse_em);
    k_trans2<<<(NROWS + 63)/64, 256, 0, stream>>>(tlembs, P0, P1, tm_bias,
                                                  tn_g, tn_beta, (const short*)tdw_bf,
                                                  td_b, lse_t);
    k_gather<<<dim3(Bb, Tt/64), 64, 0, stream>>>(x, z, h, dec_W, dec_b, lse_em,
                                                 tlembs, P0, P1, tm_bias, tn_g, tn_beta,
                                                 td_W, td_b, lse_t, out);
}

// Round 3
// 560.729 us; speedup vs baseline: 2.3210x; 1.4948x over previous
//
#include <hip/hip_runtime.h>

#define Kst 256
#define Dd 256
#define Vv 50000
#define Tt 512
#define Bb 256
#define KP1 257
#define MD 512
#define NROWS (KP1*KP1)   // 66049
#define EPSf 1e-5f

#define VB2 196           // ceil(50000/256) vocab blocks for MFMA emission kernel

typedef __attribute__((ext_vector_type(8))) short short8;
typedef __attribute__((ext_vector_type(4))) short short4v;
typedef __attribute__((ext_vector_type(4))) float f32x4;
typedef __attribute__((ext_vector_type(4))) unsigned u32x4;

__device__ __forceinline__ unsigned short f2bf(float f) {
    unsigned u = __builtin_bit_cast(unsigned, f);
    unsigned r = (u + 0x7fffu + ((u >> 16) & 1u)) >> 16;
    return (unsigned short)r;
}
__device__ __forceinline__ unsigned bfpack(float lo, float hi) {
    // [bf16(lo) | bf16(hi)<<16] by truncation: 1 v_perm_b32
    return __builtin_amdgcn_perm(__builtin_bit_cast(unsigned, hi),
                                 __builtin_bit_cast(unsigned, lo), 0x07060302u);
}

// ---------------- K1: emission hidden h = LN(lembs + relu(lembs@em_W.T + b)) (also bf16 copy) ----------------
__global__ __launch_bounds__(256) void k_h(
    const float* __restrict__ lembs, const float* __restrict__ em_W,
    const float* __restrict__ em_bias, const float* __restrict__ em_g,
    const float* __restrict__ em_beta, float* __restrict__ h,
    unsigned short* __restrict__ h_bf)
{
    int k = blockIdx.x, d = threadIdx.x;
    __shared__ float lrow[Dd];
    __shared__ float red[256];
    lrow[d] = lembs[k*Dd + d];
    __syncthreads();
    float acc = em_bias[d];
    const float4* w4 = (const float4*)(em_W + (size_t)d*Dd);
    for (int j4 = 0; j4 < Dd/4; ++j4) {
        float4 w = w4[j4];
        acc += w.x*lrow[4*j4] + w.y*lrow[4*j4+1] + w.z*lrow[4*j4+2] + w.w*lrow[4*j4+3];
    }
    float val = lrow[d] + fmaxf(acc, 0.f);
    red[d] = val; __syncthreads();
    for (int s = 128; s > 0; s >>= 1) { if (d < s) red[d] += red[d+s]; __syncthreads(); }
    float mu = red[0] * (1.f/Dd);
    __syncthreads();
    float c = val - mu;
    red[d] = c*c; __syncthreads();
    for (int s = 128; s > 0; s >>= 1) { if (d < s) red[d] += red[d+s]; __syncthreads(); }
    float rstd = rsqrtf(red[0] * (1.f/Dd) + EPSf);
    float o = c * rstd * em_g[d] + em_beta[d];
    h[k*Dd + d] = o;
    h_bf[k*Dd + d] = f2bf(o);
}

// ---------------- K2: P0[i,j] = tlembs[i]@tm_W[j,0:256], P1[i,j] = tlembs[i]@tm_W[j,256:512] ----------------
__global__ __launch_bounds__(256) void k_P(
    const float* __restrict__ tlembs, const float* __restrict__ tm_W,
    float* __restrict__ P0, float* __restrict__ P1)
{
    int i = blockIdx.x;            // 0..256
    int tid = threadIdx.x;
    __shared__ float tl[Dd];
    tl[tid] = tlembs[i*Dd + tid];
    __syncthreads();
    for (int half = 0; half < 2; ++half) {
        int j = tid + half*256;
        float a0 = 0.f, a1 = 0.f;
        const float4* w4 = (const float4*)(tm_W + (size_t)j*MD);
        for (int l4 = 0; l4 < 64; ++l4) {
            float4 w = w4[l4];
            a0 += w.x*tl[4*l4] + w.y*tl[4*l4+1] + w.z*tl[4*l4+2] + w.w*tl[4*l4+3];
        }
        for (int l4 = 64; l4 < 128; ++l4) {
            float4 w = w4[l4];
            int l = 4*l4 - 256;
            a1 += w.x*tl[l] + w.y*tl[l+1] + w.z*tl[l+2] + w.w*tl[l+3];
        }
        P0[(size_t)i*MD + j] = a0;
        P1[(size_t)i*MD + j] = a1;
    }
}

// ---------------- K2b: td_W -> bf16 copy ----------------
__global__ __launch_bounds__(256) void k_tdw(
    const float* __restrict__ td_W, unsigned short* __restrict__ tdw_bf)
{
    int i = blockIdx.x*256 + threadIdx.x;
    float4 v = ((const float4*)td_W)[i];
    short4v o;
    o.x = (short)f2bf(v.x); o.y = (short)f2bf(v.y);
    o.z = (short)f2bf(v.z); o.w = (short)f2bf(v.w);
    *(short4v*)(tdw_bf + (size_t)i*4) = o;
}

// ---------------- K2c: G[zc]=sum g_j*tdW[zc][j], Bt[zc]=sum beta_j*tdW[zc][j] ----------------
__global__ __launch_bounds__(64) void k_gtab(
    const float* __restrict__ td_W, const float* __restrict__ tn_g,
    const float* __restrict__ tn_beta, float* __restrict__ Gt, float* __restrict__ Bt)
{
    int zc = blockIdx.x, lane = threadIdx.x;
    const float4* w4 = (const float4*)(td_W + (size_t)zc*MD);
    const float4* g4 = (const float4*)tn_g;
    const float4* b4 = (const float4*)tn_beta;
    float sg = 0.f, sb = 0.f;
    #pragma unroll
    for (int u = 0; u < 2; ++u) {
        int j4 = lane*2 + u;
        float4 w = w4[j4], g = g4[j4], bt = b4[j4];
        sg += w.x*g.x + w.y*g.y + w.z*g.z + w.w*g.w;
        sb += w.x*bt.x + w.y*bt.y + w.z*bt.z + w.w*bt.w;
    }
    #pragma unroll
    for (int dd = 32; dd > 0; dd >>= 1) {
        sg += __shfl_xor(sg, dd);
        sb += __shfl_xor(sb, dd);
    }
    if (lane == 0) { Gt[zc] = sg; Bt[zc] = sb; }
}

// ---------------- K3 (MFMA): emission logsumexp partials ----------------
// C[v][k] = dec_W @ h^T : block = 4 waves, M=256 vocab rows (64/wave), N=64 k-states (kg).
// A: dec_W f32 rows -> in-register bf16 pack (v_perm). B: h_bf16 rows from LDS.
__global__ __launch_bounds__(256) void k_em_mfma(
    const float* __restrict__ dec_W, const float* __restrict__ dec_b,
    const unsigned short* __restrict__ h_bf, float* __restrict__ part)
{
    int vb = blockIdx.x, kg = blockIdx.y;
    int tid = threadIdx.x, lane = tid & 63, wv = tid >> 6;
    int l15 = lane & 15, q = lane >> 4;
    __shared__ short hs[64][264];      // stride 264: 2-way bank aliasing (free)
    __shared__ float red[4][64];
    __shared__ float gmax[64];

    // stage h_bf rows [kg*64, kg*64+64)
    {
        int row = tid >> 2, c0 = (tid & 3) * 64;
        const short8* src = (const short8*)(h_bf + (size_t)(kg*64 + row)*Dd + c0);
        #pragma unroll
        for (int u = 0; u < 8; ++u)
            *(short8*)&hs[row][c0 + u*8] = src[u];
    }
    __syncthreads();

    const float* aptr[4];
    #pragma unroll
    for (int mt = 0; mt < 4; ++mt) {
        int v = vb*256 + wv*64 + mt*16 + l15;
        if (v > Vv-1) v = Vv-1;
        aptr[mt] = dec_W + (size_t)v*Dd + q*8;
    }
    f32x4 acc[4][4];
    #pragma unroll
    for (int mt = 0; mt < 4; ++mt)
        #pragma unroll
        for (int nt = 0; nt < 4; ++nt)
            acc[mt][nt] = (f32x4){0.f,0.f,0.f,0.f};

    for (int ks = 0; ks < 8; ++ks) {
        short8 a[4];
        #pragma unroll
        for (int mt = 0; mt < 4; ++mt) {
            float4 f0 = *(const float4*)(aptr[mt] + ks*32);
            float4 f1 = *(const float4*)(aptr[mt] + ks*32 + 4);
            u32x4 pk;
            pk.x = bfpack(f0.x, f0.y);
            pk.y = bfpack(f0.z, f0.w);
            pk.z = bfpack(f1.x, f1.y);
            pk.w = bfpack(f1.z, f1.w);
            a[mt] = __builtin_bit_cast(short8, pk);
        }
        short8 b0 = *(const short8*)&hs[ 0 + l15][ks*32 + q*8];
        short8 b1 = *(const short8*)&hs[16 + l15][ks*32 + q*8];
        short8 b2 = *(const short8*)&hs[32 + l15][ks*32 + q*8];
        short8 b3 = *(const short8*)&hs[48 + l15][ks*32 + q*8];
        #pragma unroll
        for (int mt = 0; mt < 4; ++mt) {
            acc[mt][0] = __builtin_amdgcn_mfma_f32_16x16x32_bf16(a[mt], b0, acc[mt][0], 0,0,0);
            acc[mt][1] = __builtin_amdgcn_mfma_f32_16x16x32_bf16(a[mt], b1, acc[mt][1], 0,0,0);
            acc[mt][2] = __builtin_amdgcn_mfma_f32_16x16x32_bf16(a[mt], b2, acc[mt][2], 0,0,0);
            acc[mt][3] = __builtin_amdgcn_mfma_f32_16x16x32_bf16(a[mt], b3, acc[mt][3], 0,0,0);
        }
    }

    // add dec_b, mask OOB rows (C layout: row = q*4+reg within 16-tile, col = nt*16+l15)
    #pragma unroll
    for (int mt = 0; mt < 4; ++mt) {
        int vbase = vb*256 + wv*64 + mt*16 + q*4;
        #pragma unroll
        for (int reg = 0; reg < 4; ++reg) {
            int v = vbase + reg;
            if (v < Vv) {
                float db = dec_b[v];
                #pragma unroll
                for (int nt = 0; nt < 4; ++nt) acc[mt][nt][reg] += db;
            } else {
                #pragma unroll
                for (int nt = 0; nt < 4; ++nt) acc[mt][nt][reg] = -1e30f;
            }
        }
    }
    // per-col max over the wave's 64 rows
    float mxl[4];
    #pragma unroll
    for (int nt = 0; nt < 4; ++nt) {
        float m = -1e30f;
        #pragma unroll
        for (int mt = 0; mt < 4; ++mt)
            #pragma unroll
            for (int reg = 0; reg < 4; ++reg)
                m = fmaxf(m, acc[mt][nt][reg]);
        m = fmaxf(m, __shfl_xor(m, 16));
        m = fmaxf(m, __shfl_xor(m, 32));
        mxl[nt] = m;
    }
    if (q == 0)
        #pragma unroll
        for (int nt = 0; nt < 4; ++nt) red[wv][nt*16 + l15] = mxl[nt];
    __syncthreads();
    if (tid < 64)
        gmax[tid] = fmaxf(fmaxf(red[0][tid], red[1][tid]), fmaxf(red[2][tid], red[3][tid]));
    __syncthreads();
    #pragma unroll
    for (int nt = 0; nt < 4; ++nt) {
        float g = gmax[nt*16 + l15];
        float s = 0.f;
        #pragma unroll
        for (int mt = 0; mt < 4; ++mt)
            #pragma unroll
            for (int reg = 0; reg < 4; ++reg)
                s += __expf(acc[mt][nt][reg] - g);
        s += __shfl_xor(s, 16);
        s += __shfl_xor(s, 32);
        mxl[nt] = s;
    }
    __syncthreads();              // gmax reads done before red reuse
    if (q == 0)
        #pragma unroll
        for (int nt = 0; nt < 4; ++nt) red[wv][nt*16 + l15] = mxl[nt];
    __syncthreads();
    if (tid < 64) {
        int kst = kg*64 + tid;
        float s = red[0][tid] + red[1][tid] + red[2][tid] + red[3][tid];
        part[((size_t)kst*VB2 + vb)*2]     = gmax[tid];
        part[((size_t)kst*VB2 + vb)*2 + 1] = s;
    }
}

// ---------------- K4: combine partials -> lse_em[k] ----------------
__global__ __launch_bounds__(256) void k_em_comb(
    const float* __restrict__ part, float* __restrict__ lse_em)
{
    int k = threadIdx.x;
    float m = -1e30f, s = 0.f;
    for (int vb = 0; vb < VB2; ++vb) {
        float m2 = part[((size_t)k*VB2+vb)*2], s2 = part[((size_t)k*VB2+vb)*2+1];
        if (m2 > m) { s = s*__expf(m - m2) + s2; m = m2; }
        else          s += s2*__expf(m2 - m);
    }
    lse_em[k] = m + logf(s);
}

// ---------------- K5 (MFMA): transition rows -> lse_t[r] ----------------
__global__ __launch_bounds__(256) void k_trans2(
    const float* __restrict__ tlembs, const float* __restrict__ P0,
    const float* __restrict__ P1, const float* __restrict__ tm_bias,
    const float* __restrict__ tn_g, const float* __restrict__ tn_beta,
    const short* __restrict__ tdw_bf, const float* __restrict__ td_b,
    float* __restrict__ lse_t)
{
    __shared__ short th[64][520];
    __shared__ float pmax[4][64], psum[4][64], gmax[64];
    int tid = threadIdx.x, lane = tid & 63, wv = tid >> 6;
    int r0 = blockIdx.x * 64;

    int j = lane * 4;
    float4 ba  = *(const float4*)(tm_bias + j);
    float4 bb  = *(const float4*)(tm_bias + 256 + j);
    float4 ga  = *(const float4*)(tn_g + j);
    float4 gb  = *(const float4*)(tn_g + 256 + j);
    float4 bta = *(const float4*)(tn_beta + j);
    float4 btb = *(const float4*)(tn_beta + 256 + j);
    for (int i = 0; i < 16; ++i) {
        int row = wv*16 + i;
        int r = r0 + row; if (r >= NROWS) r = NROWS - 1;
        int i0 = r / KP1, i1 = r - i0*KP1;
        float4 p0a = *(const float4*)(P0 + (size_t)i0*MD + j);
        float4 p0b = *(const float4*)(P0 + (size_t)i0*MD + 256 + j);
        float4 p1a = *(const float4*)(P1 + (size_t)i1*MD + j);
        float4 p1b = *(const float4*)(P1 + (size_t)i1*MD + 256 + j);
        float4 ca  = *(const float4*)(tlembs + (size_t)i0*Dd + j);
        float4 cb  = *(const float4*)(tlembs + (size_t)i1*Dd + j);
        float v0 = ca.x + fmaxf(p0a.x + p1a.x + ba.x, 0.f);
        float v1 = ca.y + fmaxf(p0a.y + p1a.y + ba.y, 0.f);
        float v2 = ca.z + fmaxf(p0a.z + p1a.z + ba.z, 0.f);
        float v3 = ca.w + fmaxf(p0a.w + p1a.w + ba.w, 0.f);
        float v4 = cb.x + fmaxf(p0b.x + p1b.x + bb.x, 0.f);
        float v5 = cb.y + fmaxf(p0b.y + p1b.y + bb.y, 0.f);
        float v6 = cb.z + fmaxf(p0b.z + p1b.z + bb.z, 0.f);
        float v7 = cb.w + fmaxf(p0b.w + p1b.w + bb.w, 0.f);
        float s  = ((v0+v1)+(v2+v3)) + ((v4+v5)+(v6+v7));
        float ss = ((v0*v0+v1*v1)+(v2*v2+v3*v3)) + ((v4*v4+v5*v5)+(v6*v6+v7*v7));
        #pragma unroll
        for (int d = 1; d < 64; d <<= 1) {
            s  += __shfl_xor(s, d);
            ss += __shfl_xor(ss, d);
        }
        float mu = s * (1.f/MD);
        float rstd = rsqrtf(ss*(1.f/MD) - mu*mu + EPSf);
        short4v oa, ob;
        oa.x = (short)f2bf((v0-mu)*rstd*ga.x + bta.x);
        oa.y = (short)f2bf((v1-mu)*rstd*ga.y + bta.y);
        oa.z = (short)f2bf((v2-mu)*rstd*ga.z + bta.z);
        oa.w = (short)f2bf((v3-mu)*rstd*ga.w + bta.w);
        ob.x = (short)f2bf((v4-mu)*rstd*gb.x + btb.x);
        ob.y = (short)f2bf((v5-mu)*rstd*gb.y + btb.y);
        ob.z = (short)f2bf((v6-mu)*rstd*gb.z + btb.z);
        ob.w = (short)f2bf((v7-mu)*rstd*gb.w + btb.w);
        *(short4v*)&th[row][j]       = oa;
        *(short4v*)&th[row][256 + j] = ob;
    }
    __syncthreads();

    int l15 = lane & 15, q = lane >> 4;
    f32x4 acc[4][4];
    #pragma unroll
    for (int rt = 0; rt < 4; ++rt)
        #pragma unroll
        for (int ct = 0; ct < 4; ++ct)
            acc[rt][ct] = (f32x4){0.f, 0.f, 0.f, 0.f};
    const short* tb = tdw_bf + ((size_t)(wv*64 + l15))*MD + q*8;
    #pragma unroll 4
    for (int ks = 0; ks < 16; ++ks) {
        int ko = ks*32 + q*8;
        short8 a0 = *(const short8*)&th[ 0 + l15][ko];
        short8 a1 = *(const short8*)&th[16 + l15][ko];
        short8 a2 = *(const short8*)&th[32 + l15][ko];
        short8 a3 = *(const short8*)&th[48 + l15][ko];
        short8 b0 = *(const short8*)(tb + ks*32);
        short8 b1 = *(const short8*)(tb + 16*MD + ks*32);
        short8 b2 = *(const short8*)(tb + 32*MD + ks*32);
        short8 b3 = *(const short8*)(tb + 48*MD + ks*32);
        acc[0][0] = __builtin_amdgcn_mfma_f32_16x16x32_bf16(a0, b0, acc[0][0], 0,0,0);
        acc[1][0] = __builtin_amdgcn_mfma_f32_16x16x32_bf16(a1, b0, acc[1][0], 0,0,0);
        acc[2][0] = __builtin_amdgcn_mfma_f32_16x16x32_bf16(a2, b0, acc[2][0], 0,0,0);
        acc[3][0] = __builtin_amdgcn_mfma_f32_16x16x32_bf16(a3, b0, acc[3][0], 0,0,0);
        acc[0][1] = __builtin_amdgcn_mfma_f32_16x16x32_bf16(a0, b1, acc[0][1], 0,0,0);
        acc[1][1] = __builtin_amdgcn_mfma_f32_16x16x32_bf16(a1, b1, acc[1][1], 0,0,0);
        acc[2][1] = __builtin_amdgcn_mfma_f32_16x16x32_bf16(a2, b1, acc[2][1], 0,0,0);
        acc[3][1] = __builtin_amdgcn_mfma_f32_16x16x32_bf16(a3, b1, acc[3][1], 0,0,0);
        acc[0][2] = __builtin_amdgcn_mfma_f32_16x16x32_bf16(a0, b2, acc[0][2], 0,0,0);
        acc[1][2] = __builtin_amdgcn_mfma_f32_16x16x32_bf16(a1, b2, acc[1][2], 0,0,0);
        acc[2][2] = __builtin_amdgcn_mfma_f32_16x16x32_bf16(a2, b2, acc[2][2], 0,0,0);
        acc[3][2] = __builtin_amdgcn_mfma_f32_16x16x32_bf16(a3, b2, acc[3][2], 0,0,0);
        acc[0][3] = __builtin_amdgcn_mfma_f32_16x16x32_bf16(a0, b3, acc[0][3], 0,0,0);
        acc[1][3] = __builtin_amdgcn_mfma_f32_16x16x32_bf16(a1, b3, acc[1][3], 0,0,0);
        acc[2][3] = __builtin_amdgcn_mfma_f32_16x16x32_bf16(a2, b3, acc[2][3], 0,0,0);
        acc[3][3] = __builtin_amdgcn_mfma_f32_16x16x32_bf16(a3, b3, acc[3][3], 0,0,0);
    }

    float tbc0 = td_b[wv*64 +  0 + l15];
    float tbc1 = td_b[wv*64 + 16 + l15];
    float tbc2 = td_b[wv*64 + 32 + l15];
    float tbc3 = td_b[wv*64 + 48 + l15];
    #pragma unroll
    for (int rt = 0; rt < 4; ++rt) {
        #pragma unroll
        for (int reg = 0; reg < 4; ++reg) {
            acc[rt][0][reg] += tbc0;
            acc[rt][1][reg] += tbc1;
            acc[rt][2][reg] += tbc2;
            acc[rt][3][reg] += tbc3;
        }
    }
    #pragma unroll
    for (int rt = 0; rt < 4; ++rt) {
        #pragma unroll
        for (int reg = 0; reg < 4; ++reg) {
            float m = fmaxf(fmaxf(acc[rt][0][reg], acc[rt][1][reg]),
                            fmaxf(acc[rt][2][reg], acc[rt][3][reg]));
            m = fmaxf(m, __shfl_xor(m, 1));
            m = fmaxf(m, __shfl_xor(m, 2));
            m = fmaxf(m, __shfl_xor(m, 4));
            m = fmaxf(m, __shfl_xor(m, 8));
            if (l15 == 0) pmax[wv][rt*16 + q*4 + reg] = m;
        }
    }
    __syncthreads();
    if (tid < 64)
        gmax[tid] = fmaxf(fmaxf(pmax[0][tid], pmax[1][tid]),
                          fmaxf(pmax[2][tid], pmax[3][tid]));
    __syncthreads();
    #pragma unroll
    for (int rt = 0; rt < 4; ++rt) {
        #pragma unroll
        for (int reg = 0; reg < 4; ++reg) {
            int row = rt*16 + q*4 + reg;
            float g = gmax[row];
            float s = __expf(acc[rt][0][reg] - g) + __expf(acc[rt][1][reg] - g)
                    + __expf(acc[rt][2][reg] - g) + __expf(acc[rt][3][reg] - g);
            s += __shfl_xor(s, 1);
            s += __shfl_xor(s, 2);
            s += __shfl_xor(s, 4);
            s += __shfl_xor(s, 8);
            if (l15 == 0) psum[wv][row] = s;
        }
    }
    __syncthreads();
    if (tid < 64) {
        int r = r0 + tid;
        if (r < NROWS)
            lse_t[r] = gmax[tid] + logf(psum[0][tid] + psum[1][tid] + psum[2][tid] + psum[3][tid]);
    }
}

// ---------------- K6: per-(t,b) gather (single-pass LN via G/Bt decomposition) ----------------
__global__ __launch_bounds__(64) void k_gather(
    const int* __restrict__ x, const int* __restrict__ z,
    const float* __restrict__ h, const float* __restrict__ dec_W,
    const float* __restrict__ dec_b, const float* __restrict__ lse_em,
    const float* __restrict__ tlembs, const float* __restrict__ P0,
    const float* __restrict__ P1, const float* __restrict__ tm_bias,
    const float* __restrict__ tn_g, const float* __restrict__ Gt,
    const float* __restrict__ Bt, const float* __restrict__ td_W,
    const float* __restrict__ td_b, const float* __restrict__ lse_t,
    float* __restrict__ out)
{
    int b = blockIdx.x;
    int t = blockIdx.y * 64 + threadIdx.x;
    int zc = z[t*Bb + b];
    int xv = x[t*Bb + b];
    float total;
    {   // emission term
        const float4* hw = (const float4*)(h + (size_t)zc*Dd);
        const float4* dw = (const float4*)(dec_W + (size_t)xv*Dd);
        float acc = 0.f;
        for (int l4 = 0; l4 < Dd/4; ++l4) {
            float4 a = hw[l4], w = dw[l4];
            acc += a.x*w.x + a.y*w.y + a.z*w.z + a.w*w.w;
        }
        total = acc + dec_b[xv] - lse_em[zc];
    }
    {   // transition term, single pass: stats + H = sum h*g*w together
        int i0 = (t >= 2) ? z[(t-2)*Bb + b] : Kst;
        int i1 = (t >= 1) ? z[(t-1)*Bb + b] : Kst;
        const float4* p0 = (const float4*)(P0 + (size_t)i0*MD);
        const float4* p1 = (const float4*)(P1 + (size_t)i1*MD);
        const float4* c0 = (const float4*)(tlembs + (size_t)i0*Dd);
        const float4* c1 = (const float4*)(tlembs + (size_t)i1*Dd);
        const float4* bj = (const float4*)tm_bias;
        const float4* gg = (const float4*)tn_g;
        const float4* wr = (const float4*)(td_W + (size_t)zc*MD);
        float s = 0.f, ss = 0.f, Hh = 0.f;
        for (int j4 = 0; j4 < MD/4; ++j4) {
            float4 a = p0[j4], bb = p1[j4], c = bj[j4];
            float4 cat = (j4 < 64) ? c0[j4] : c1[j4-64];
            float h0 = cat.x + fmaxf(a.x+bb.x+c.x, 0.f);
            float h1 = cat.y + fmaxf(a.y+bb.y+c.y, 0.f);
            float h2 = cat.z + fmaxf(a.z+bb.z+c.z, 0.f);
            float h3 = cat.w + fmaxf(a.w+bb.w+c.w, 0.f);
            s  += (h0+h1) + (h2+h3);
            ss += (h0*h0+h1*h1) + (h2*h2+h3*h3);
            float4 g = gg[j4], w = wr[j4];
            Hh += h0*g.x*w.x + h1*g.y*w.y + h2*g.z*w.z + h3*g.w*w.w;
        }
        float mu = s * (1.f/MD);
        float rstd = rsqrtf(ss*(1.f/MD) - mu*mu + EPSf);
        total += rstd*(Hh - mu*Gt[zc]) + Bt[zc] + td_b[zc] - lse_t[i0*KP1 + i1];
    }
    for (int dd = 32; dd > 0; dd >>= 1) total += __shfl_down(total, dd);
    if (threadIdx.x == 0) atomicAdd(&out[b], total);
}

extern "C" void kernel_launch(void* const* d_in, const int* in_sizes, int n_in,
                              void* d_out, int out_size, void* d_ws, size_t ws_size,
                              hipStream_t stream)
{
    const int*   x       = (const int*)  d_in[0];
    const int*   z       = (const int*)  d_in[1];
    const float* lembs   = (const float*)d_in[2];
    const float* tlembs  = (const float*)d_in[3];
    const float* dec_W   = (const float*)d_in[4];
    const float* dec_b   = (const float*)d_in[5];
    const float* em_W    = (const float*)d_in[6];
    const float* em_bias = (const float*)d_in[7];
    const float* em_g    = (const float*)d_in[8];
    const float* em_beta = (const float*)d_in[9];
    const float* td_W    = (const float*)d_in[10];
    const float* td_b    = (const float*)d_in[11];
    const float* tm_W    = (const float*)d_in[12];
    const float* tm_bias = (const float*)d_in[13];
    const float* tn_g    = (const float*)d_in[14];
    const float* tn_beta = (const float*)d_in[15];
    float* out = (float*)d_out;

    float* ws     = (float*)d_ws;
    float* h      = ws;                    // 65536
    float* P0     = h + 65536;             // 131584
    float* P1     = P0 + 131584;           // 131584
    float* lse_em = P1 + 131584;           // 256
    float* part   = lse_em + 256;          // 256*196*2 = 100352
    float* lse_t  = part + 100352;         // 66049
    float* Gt     = lse_t + 66049 + 3;     // 256
    float* Bt     = Gt + 256;              // 256
    unsigned short* tdw_bf = (unsigned short*)(Bt + 256);   // 256*512 bf16 = 262144 B
    unsigned short* h_bf   = tdw_bf + 131072;               // 256*256 bf16 = 131072 B
    // total ~2.4 MB of workspace

    hipMemsetAsync(out, 0, Bb*sizeof(float), stream);
    k_h<<<Kst, 256, 0, stream>>>(lembs, em_W, em_bias, em_g, em_beta, h, h_bf);
    k_P<<<KP1, 256, 0, stream>>>(tlembs, tm_W, P0, P1);
    k_tdw<<<128, 256, 0, stream>>>(td_W, tdw_bf);
    k_gtab<<<Kst, 64, 0, stream>>>(td_W, tn_g, tn_beta, Gt, Bt);
    k_em_mfma<<<dim3(VB2, 4), 256, 0, stream>>>(dec_W, dec_b, h_bf, part);
    k_em_comb<<<1, Kst, 0, stream>>>(part, lse_em);
    k_trans2<<<(NROWS + 63)/64, 256, 0, stream>>>(tlembs, P0, P1, tm_bias,
                                                  tn_g, tn_beta, (const short*)tdw_bf,
                                                  td_b, lse_t);
    k_gather<<<dim3(Bb, Tt/64), 64, 0, stream>>>(x, z, h, dec_W, dec_b, lse_em,
                                                 tlembs, P0, P1, tm_bias, tn_g, Gt, Bt,
                                                 td_W, td_b, lse_t, out);
}

// Round 4
// 400.322 us; speedup vs baseline: 3.2510x; 1.4007x over previous
//
#include <hip/hip_runtime.h>

#define Kst 256
#define Dd 256
#define Vv 50000
#define Tt 512
#define Bb 256
#define KP1 257
#define MD 512
#define NROWS (KP1*KP1)   // 66049
#define EPSf 1e-5f

#define VB2 196           // ceil(50000/256) vocab blocks for MFMA emission kernel

typedef __attribute__((ext_vector_type(8))) short short8;
typedef __attribute__((ext_vector_type(4))) short short4v;
typedef __attribute__((ext_vector_type(4))) float f32x4;
typedef __attribute__((ext_vector_type(4))) unsigned u32x4;

__device__ __forceinline__ unsigned short f2bf(float f) {
    unsigned u = __builtin_bit_cast(unsigned, f);
    unsigned r = (u + 0x7fffu + ((u >> 16) & 1u)) >> 16;
    return (unsigned short)r;
}
__device__ __forceinline__ float bf2f(unsigned short u) {
    return __builtin_bit_cast(float, ((unsigned)u) << 16);
}
__device__ __forceinline__ unsigned bfpack(float lo, float hi) {
    return __builtin_amdgcn_perm(__builtin_bit_cast(unsigned, hi),
                                 __builtin_bit_cast(unsigned, lo), 0x07060302u);
}

// ---------------- K1: emission hidden h = LN(lembs + relu(lembs@em_W.T + b)) -> bf16 ----------------
__global__ __launch_bounds__(256) void k_h(
    const float* __restrict__ lembs, const float* __restrict__ em_W,
    const float* __restrict__ em_bias, const float* __restrict__ em_g,
    const float* __restrict__ em_beta, unsigned short* __restrict__ h_bf)
{
    int k = blockIdx.x, d = threadIdx.x;
    __shared__ float lrow[Dd];
    __shared__ float red[256];
    lrow[d] = lembs[k*Dd + d];
    __syncthreads();
    float acc = em_bias[d];
    const float4* w4 = (const float4*)(em_W + (size_t)d*Dd);
    for (int j4 = 0; j4 < Dd/4; ++j4) {
        float4 w = w4[j4];
        acc += w.x*lrow[4*j4] + w.y*lrow[4*j4+1] + w.z*lrow[4*j4+2] + w.w*lrow[4*j4+3];
    }
    float val = lrow[d] + fmaxf(acc, 0.f);
    red[d] = val; __syncthreads();
    for (int s = 128; s > 0; s >>= 1) { if (d < s) red[d] += red[d+s]; __syncthreads(); }
    float mu = red[0] * (1.f/Dd);
    __syncthreads();
    float c = val - mu;
    red[d] = c*c; __syncthreads();
    for (int s = 128; s > 0; s >>= 1) { if (d < s) red[d] += red[d+s]; __syncthreads(); }
    float rstd = rsqrtf(red[0] * (1.f/Dd) + EPSf);
    float o = c * rstd * em_g[d] + em_beta[d];
    h_bf[k*Dd + d] = f2bf(o);
}

// ---------------- K2: P0[i,j] = tlembs[i]@tm_W[j,0:256], P1[i,j] = tlembs[i]@tm_W[j,256:512] ----------------
__global__ __launch_bounds__(256) void k_P(
    const float* __restrict__ tlembs, const float* __restrict__ tm_W,
    float* __restrict__ P0, float* __restrict__ P1)
{
    int i = blockIdx.x;            // 0..256
    int tid = threadIdx.x;
    __shared__ float tl[Dd];
    tl[tid] = tlembs[i*Dd + tid];
    __syncthreads();
    for (int half = 0; half < 2; ++half) {
        int j = tid + half*256;
        float a0 = 0.f, a1 = 0.f;
        const float4* w4 = (const float4*)(tm_W + (size_t)j*MD);
        for (int l4 = 0; l4 < 64; ++l4) {
            float4 w = w4[l4];
            a0 += w.x*tl[4*l4] + w.y*tl[4*l4+1] + w.z*tl[4*l4+2] + w.w*tl[4*l4+3];
        }
        for (int l4 = 64; l4 < 128; ++l4) {
            float4 w = w4[l4];
            int l = 4*l4 - 256;
            a1 += w.x*tl[l] + w.y*tl[l+1] + w.z*tl[l+2] + w.w*tl[l+3];
        }
        P0[(size_t)i*MD + j] = a0;
        P1[(size_t)i*MD + j] = a1;
    }
}

// ---------------- K2b: td_W -> bf16 copy ----------------
__global__ __launch_bounds__(256) void k_tdw(
    const float* __restrict__ td_W, unsigned short* __restrict__ tdw_bf)
{
    int i = blockIdx.x*256 + threadIdx.x;
    float4 v = ((const float4*)td_W)[i];
    short4v o;
    o.x = (short)f2bf(v.x); o.y = (short)f2bf(v.y);
    o.z = (short)f2bf(v.z); o.w = (short)f2bf(v.w);
    *(short4v*)(tdw_bf + (size_t)i*4) = o;
}

// ---------------- K3 (MFMA): emission logits E[v][k] (bf16) + logsumexp partials ----------------
__global__ __launch_bounds__(256) void k_em_mfma(
    const float* __restrict__ dec_W, const float* __restrict__ dec_b,
    const unsigned short* __restrict__ h_bf, float* __restrict__ part,
    unsigned short* __restrict__ E)
{
    int vb = blockIdx.x, kg = blockIdx.y;
    int tid = threadIdx.x, lane = tid & 63, wv = tid >> 6;
    int l15 = lane & 15, q = lane >> 4;
    __shared__ short hs[64][264];      // stride 264: 2-way bank aliasing (free)
    __shared__ float red[4][64];
    __shared__ float gmax[64];

    {
        int row = tid >> 2, c0 = (tid & 3) * 64;
        const short8* src = (const short8*)(h_bf + (size_t)(kg*64 + row)*Dd + c0);
        #pragma unroll
        for (int u = 0; u < 8; ++u)
            *(short8*)&hs[row][c0 + u*8] = src[u];
    }
    __syncthreads();

    const float* aptr[4];
    #pragma unroll
    for (int mt = 0; mt < 4; ++mt) {
        int v = vb*256 + wv*64 + mt*16 + l15;
        if (v > Vv-1) v = Vv-1;
        aptr[mt] = dec_W + (size_t)v*Dd + q*8;
    }
    f32x4 acc[4][4];
    #pragma unroll
    for (int mt = 0; mt < 4; ++mt)
        #pragma unroll
        for (int nt = 0; nt < 4; ++nt)
            acc[mt][nt] = (f32x4){0.f,0.f,0.f,0.f};

    for (int ks = 0; ks < 8; ++ks) {
        short8 a[4];
        #pragma unroll
        for (int mt = 0; mt < 4; ++mt) {
            float4 f0 = *(const float4*)(aptr[mt] + ks*32);
            float4 f1 = *(const float4*)(aptr[mt] + ks*32 + 4);
            u32x4 pk;
            pk.x = bfpack(f0.x, f0.y);
            pk.y = bfpack(f0.z, f0.w);
            pk.z = bfpack(f1.x, f1.y);
            pk.w = bfpack(f1.z, f1.w);
            a[mt] = __builtin_bit_cast(short8, pk);
        }
        short8 b0 = *(const short8*)&hs[ 0 + l15][ks*32 + q*8];
        short8 b1 = *(const short8*)&hs[16 + l15][ks*32 + q*8];
        short8 b2 = *(const short8*)&hs[32 + l15][ks*32 + q*8];
        short8 b3 = *(const short8*)&hs[48 + l15][ks*32 + q*8];
        #pragma unroll
        for (int mt = 0; mt < 4; ++mt) {
            acc[mt][0] = __builtin_amdgcn_mfma_f32_16x16x32_bf16(a[mt], b0, acc[mt][0], 0,0,0);
            acc[mt][1] = __builtin_amdgcn_mfma_f32_16x16x32_bf16(a[mt], b1, acc[mt][1], 0,0,0);
            acc[mt][2] = __builtin_amdgcn_mfma_f32_16x16x32_bf16(a[mt], b2, acc[mt][2], 0,0,0);
            acc[mt][3] = __builtin_amdgcn_mfma_f32_16x16x32_bf16(a[mt], b3, acc[mt][3], 0,0,0);
        }
    }

    // add dec_b, store bf16 logits, mask OOB rows (C layout: row=q*4+reg, col=nt*16+l15)
    #pragma unroll
    for (int mt = 0; mt < 4; ++mt) {
        int vbase = vb*256 + wv*64 + mt*16 + q*4;
        #pragma unroll
        for (int reg = 0; reg < 4; ++reg) {
            int v = vbase + reg;
            if (v < Vv) {
                float db = dec_b[v];
                #pragma unroll
                for (int nt = 0; nt < 4; ++nt) {
                    acc[mt][nt][reg] += db;
                    E[(size_t)v*Kst + kg*64 + nt*16 + l15] = f2bf(acc[mt][nt][reg]);
                }
            } else {
                #pragma unroll
                for (int nt = 0; nt < 4; ++nt) acc[mt][nt][reg] = -1e30f;
            }
        }
    }
    float mxl[4];
    #pragma unroll
    for (int nt = 0; nt < 4; ++nt) {
        float m = -1e30f;
        #pragma unroll
        for (int mt = 0; mt < 4; ++mt)
            #pragma unroll
            for (int reg = 0; reg < 4; ++reg)
                m = fmaxf(m, acc[mt][nt][reg]);
        m = fmaxf(m, __shfl_xor(m, 16));
        m = fmaxf(m, __shfl_xor(m, 32));
        mxl[nt] = m;
    }
    if (q == 0)
        #pragma unroll
        for (int nt = 0; nt < 4; ++nt) red[wv][nt*16 + l15] = mxl[nt];
    __syncthreads();
    if (tid < 64)
        gmax[tid] = fmaxf(fmaxf(red[0][tid], red[1][tid]), fmaxf(red[2][tid], red[3][tid]));
    __syncthreads();
    #pragma unroll
    for (int nt = 0; nt < 4; ++nt) {
        float g = gmax[nt*16 + l15];
        float s = 0.f;
        #pragma unroll
        for (int mt = 0; mt < 4; ++mt)
            #pragma unroll
            for (int reg = 0; reg < 4; ++reg)
                s += __expf(acc[mt][nt][reg] - g);
        s += __shfl_xor(s, 16);
        s += __shfl_xor(s, 32);
        mxl[nt] = s;
    }
    __syncthreads();
    if (q == 0)
        #pragma unroll
        for (int nt = 0; nt < 4; ++nt) red[wv][nt*16 + l15] = mxl[nt];
    __syncthreads();
    if (tid < 64) {
        int kst = kg*64 + tid;
        float s = red[0][tid] + red[1][tid] + red[2][tid] + red[3][tid];
        part[((size_t)kst*VB2 + vb)*2]     = gmax[tid];
        part[((size_t)kst*VB2 + vb)*2 + 1] = s;
    }
}

// ---------------- K4: combine partials -> lse_em[k] ----------------
__global__ __launch_bounds__(256) void k_em_comb(
    const float* __restrict__ part, float* __restrict__ lse_em)
{
    int k = threadIdx.x;
    float m = -1e30f, s = 0.f;
    for (int vb = 0; vb < VB2; ++vb) {
        float m2 = part[((size_t)k*VB2+vb)*2], s2 = part[((size_t)k*VB2+vb)*2+1];
        if (m2 > m) { s = s*__expf(m - m2) + s2; m = m2; }
        else          s += s2*__expf(m2 - m);
    }
    lse_em[k] = m + logf(s);
}

// ---------------- K5 (MFMA): transition logits Td[r][c] (bf16) + lse_t[r] ----------------
__global__ __launch_bounds__(256) void k_trans2(
    const float* __restrict__ tlembs, const float* __restrict__ P0,
    const float* __restrict__ P1, const float* __restrict__ tm_bias,
    const float* __restrict__ tn_g, const float* __restrict__ tn_beta,
    const short* __restrict__ tdw_bf, const float* __restrict__ td_b,
    float* __restrict__ lse_t, unsigned short* __restrict__ Td)
{
    __shared__ short th[64][520];
    __shared__ float pmax[4][64], psum[4][64], gmax[64];
    int tid = threadIdx.x, lane = tid & 63, wv = tid >> 6;
    int r0 = blockIdx.x * 64;

    int j = lane * 4;
    float4 ba  = *(const float4*)(tm_bias + j);
    float4 bb  = *(const float4*)(tm_bias + 256 + j);
    float4 ga  = *(const float4*)(tn_g + j);
    float4 gb  = *(const float4*)(tn_g + 256 + j);
    float4 bta = *(const float4*)(tn_beta + j);
    float4 btb = *(const float4*)(tn_beta + 256 + j);
    for (int i = 0; i < 16; ++i) {
        int row = wv*16 + i;
        int r = r0 + row; if (r >= NROWS) r = NROWS - 1;
        int i0 = r / KP1, i1 = r - i0*KP1;
        float4 p0a = *(const float4*)(P0 + (size_t)i0*MD + j);
        float4 p0b = *(const float4*)(P0 + (size_t)i0*MD + 256 + j);
        float4 p1a = *(const float4*)(P1 + (size_t)i1*MD + j);
        float4 p1b = *(const float4*)(P1 + (size_t)i1*MD + 256 + j);
        float4 ca  = *(const float4*)(tlembs + (size_t)i0*Dd + j);
        float4 cb  = *(const float4*)(tlembs + (size_t)i1*Dd + j);
        float v0 = ca.x + fmaxf(p0a.x + p1a.x + ba.x, 0.f);
        float v1 = ca.y + fmaxf(p0a.y + p1a.y + ba.y, 0.f);
        float v2 = ca.z + fmaxf(p0a.z + p1a.z + ba.z, 0.f);
        float v3 = ca.w + fmaxf(p0a.w + p1a.w + ba.w, 0.f);
        float v4 = cb.x + fmaxf(p0b.x + p1b.x + bb.x, 0.f);
        float v5 = cb.y + fmaxf(p0b.y + p1b.y + bb.y, 0.f);
        float v6 = cb.z + fmaxf(p0b.z + p1b.z + bb.z, 0.f);
        float v7 = cb.w + fmaxf(p0b.w + p1b.w + bb.w, 0.f);
        float s  = ((v0+v1)+(v2+v3)) + ((v4+v5)+(v6+v7));
        float ss = ((v0*v0+v1*v1)+(v2*v2+v3*v3)) + ((v4*v4+v5*v5)+(v6*v6+v7*v7));
        #pragma unroll
        for (int d = 1; d < 64; d <<= 1) {
            s  += __shfl_xor(s, d);
            ss += __shfl_xor(ss, d);
        }
        float mu = s * (1.f/MD);
        float rstd = rsqrtf(ss*(1.f/MD) - mu*mu + EPSf);
        short4v oa, ob;
        oa.x = (short)f2bf((v0-mu)*rstd*ga.x + bta.x);
        oa.y = (short)f2bf((v1-mu)*rstd*ga.y + bta.y);
        oa.z = (short)f2bf((v2-mu)*rstd*ga.z + bta.z);
        oa.w = (short)f2bf((v3-mu)*rstd*ga.w + bta.w);
        ob.x = (short)f2bf((v4-mu)*rstd*gb.x + btb.x);
        ob.y = (short)f2bf((v5-mu)*rstd*gb.y + btb.y);
        ob.z = (short)f2bf((v6-mu)*rstd*gb.z + btb.z);
        ob.w = (short)f2bf((v7-mu)*rstd*gb.w + btb.w);
        *(short4v*)&th[row][j]       = oa;
        *(short4v*)&th[row][256 + j] = ob;
    }
    __syncthreads();

    int l15 = lane & 15, q = lane >> 4;
    f32x4 acc[4][4];
    #pragma unroll
    for (int rt = 0; rt < 4; ++rt)
        #pragma unroll
        for (int ct = 0; ct < 4; ++ct)
            acc[rt][ct] = (f32x4){0.f, 0.f, 0.f, 0.f};
    const short* tb = tdw_bf + ((size_t)(wv*64 + l15))*MD + q*8;
    #pragma unroll 4
    for (int ks = 0; ks < 16; ++ks) {
        int ko = ks*32 + q*8;
        short8 a0 = *(const short8*)&th[ 0 + l15][ko];
        short8 a1 = *(const short8*)&th[16 + l15][ko];
        short8 a2 = *(const short8*)&th[32 + l15][ko];
        short8 a3 = *(const short8*)&th[48 + l15][ko];
        short8 b0 = *(const short8*)(tb + ks*32);
        short8 b1 = *(const short8*)(tb + 16*MD + ks*32);
        short8 b2 = *(const short8*)(tb + 32*MD + ks*32);
        short8 b3 = *(const short8*)(tb + 48*MD + ks*32);
        acc[0][0] = __builtin_amdgcn_mfma_f32_16x16x32_bf16(a0, b0, acc[0][0], 0,0,0);
        acc[1][0] = __builtin_amdgcn_mfma_f32_16x16x32_bf16(a1, b0, acc[1][0], 0,0,0);
        acc[2][0] = __builtin_amdgcn_mfma_f32_16x16x32_bf16(a2, b0, acc[2][0], 0,0,0);
        acc[3][0] = __builtin_amdgcn_mfma_f32_16x16x32_bf16(a3, b0, acc[3][0], 0,0,0);
        acc[0][1] = __builtin_amdgcn_mfma_f32_16x16x32_bf16(a0, b1, acc[0][1], 0,0,0);
        acc[1][1] = __builtin_amdgcn_mfma_f32_16x16x32_bf16(a1, b1, acc[1][1], 0,0,0);
        acc[2][1] = __builtin_amdgcn_mfma_f32_16x16x32_bf16(a2, b1, acc[2][1], 0,0,0);
        acc[3][1] = __builtin_amdgcn_mfma_f32_16x16x32_bf16(a3, b1, acc[3][1], 0,0,0);
        acc[0][2] = __builtin_amdgcn_mfma_f32_16x16x32_bf16(a0, b2, acc[0][2], 0,0,0);
        acc[1][2] = __builtin_amdgcn_mfma_f32_16x16x32_bf16(a1, b2, acc[1][2], 0,0,0);
        acc[2][2] = __builtin_amdgcn_mfma_f32_16x16x32_bf16(a2, b2, acc[2][2], 0,0,0);
        acc[3][2] = __builtin_amdgcn_mfma_f32_16x16x32_bf16(a3, b2, acc[3][2], 0,0,0);
        acc[0][3] = __builtin_amdgcn_mfma_f32_16x16x32_bf16(a0, b3, acc[0][3], 0,0,0);
        acc[1][3] = __builtin_amdgcn_mfma_f32_16x16x32_bf16(a1, b3, acc[1][3], 0,0,0);
        acc[2][3] = __builtin_amdgcn_mfma_f32_16x16x32_bf16(a2, b3, acc[2][3], 0,0,0);
        acc[3][3] = __builtin_amdgcn_mfma_f32_16x16x32_bf16(a3, b3, acc[3][3], 0,0,0);
    }

    float tbc0 = td_b[wv*64 +  0 + l15];
    float tbc1 = td_b[wv*64 + 16 + l15];
    float tbc2 = td_b[wv*64 + 32 + l15];
    float tbc3 = td_b[wv*64 + 48 + l15];
    #pragma unroll
    for (int rt = 0; rt < 4; ++rt) {
        #pragma unroll
        for (int reg = 0; reg < 4; ++reg) {
            acc[rt][0][reg] += tbc0;
            acc[rt][1][reg] += tbc1;
            acc[rt][2][reg] += tbc2;
            acc[rt][3][reg] += tbc3;
        }
    }
    // store bf16 logits (row = r0 + rt*16 + q*4 + reg, col = wv*64 + ct*16 + l15)
    #pragma unroll
    for (int rt = 0; rt < 4; ++rt) {
        #pragma unroll
        for (int reg = 0; reg < 4; ++reg) {
            int r = r0 + rt*16 + q*4 + reg;
            if (r < NROWS) {
                unsigned short* dst = Td + (size_t)r*Kst + wv*64 + l15;
                dst[ 0] = f2bf(acc[rt][0][reg]);
                dst[16] = f2bf(acc[rt][1][reg]);
                dst[32] = f2bf(acc[rt][2][reg]);
                dst[48] = f2bf(acc[rt][3][reg]);
            }
        }
    }
    #pragma unroll
    for (int rt = 0; rt < 4; ++rt) {
        #pragma unroll
        for (int reg = 0; reg < 4; ++reg) {
            float m = fmaxf(fmaxf(acc[rt][0][reg], acc[rt][1][reg]),
                            fmaxf(acc[rt][2][reg], acc[rt][3][reg]));
            m = fmaxf(m, __shfl_xor(m, 1));
            m = fmaxf(m, __shfl_xor(m, 2));
            m = fmaxf(m, __shfl_xor(m, 4));
            m = fmaxf(m, __shfl_xor(m, 8));
            if (l15 == 0) pmax[wv][rt*16 + q*4 + reg] = m;
        }
    }
    __syncthreads();
    if (tid < 64)
        gmax[tid] = fmaxf(fmaxf(pmax[0][tid], pmax[1][tid]),
                          fmaxf(pmax[2][tid], pmax[3][tid]));
    __syncthreads();
    #pragma unroll
    for (int rt = 0; rt < 4; ++rt) {
        #pragma unroll
        for (int reg = 0; reg < 4; ++reg) {
            int row = rt*16 + q*4 + reg;
            float g = gmax[row];
            float s = __expf(acc[rt][0][reg] - g) + __expf(acc[rt][1][reg] - g)
                    + __expf(acc[rt][2][reg] - g) + __expf(acc[rt][3][reg] - g);
            s += __shfl_xor(s, 1);
            s += __shfl_xor(s, 2);
            s += __shfl_xor(s, 4);
            s += __shfl_xor(s, 8);
            if (l15 == 0) psum[wv][row] = s;
        }
    }
    __syncthreads();
    if (tid < 64) {
        int r = r0 + tid;
        if (r < NROWS)
            lse_t[r] = gmax[tid] + logf(psum[0][tid] + psum[1][tid] + psum[2][tid] + psum[3][tid]);
    }
}

// ---------------- K6: gather = 2 table lookups per (t,b) ----------------
#define TCH 4
__global__ __launch_bounds__(256) void k_gather2(
    const int* __restrict__ x, const int* __restrict__ z,
    const unsigned short* __restrict__ E, const float* __restrict__ lse_em,
    const unsigned short* __restrict__ Td, const float* __restrict__ lse_t,
    float* __restrict__ out)
{
    int b = threadIdx.x;
    int t0 = blockIdx.x * TCH;
    float s = 0.f;
    #pragma unroll
    for (int i = 0; i < TCH; ++i) {
        int t = t0 + i;
        int zc = z[t*Bb + b];
        int xv = x[t*Bb + b];
        int i0 = (t >= 2) ? z[(t-2)*Bb + b] : Kst;
        int i1 = (t >= 1) ? z[(t-1)*Bb + b] : Kst;
        int lin = i0*KP1 + i1;
        float em = bf2f(E[(size_t)xv*Kst + zc])  - lse_em[zc];
        float tr = bf2f(Td[(size_t)lin*Kst + zc]) - lse_t[lin];
        s += em + tr;
    }
    atomicAdd(&out[b], s);
}

extern "C" void kernel_launch(void* const* d_in, const int* in_sizes, int n_in,
                              void* d_out, int out_size, void* d_ws, size_t ws_size,
                              hipStream_t stream)
{
    const int*   x       = (const int*)  d_in[0];
    const int*   z       = (const int*)  d_in[1];
    const float* lembs   = (const float*)d_in[2];
    const float* tlembs  = (const float*)d_in[3];
    const float* dec_W   = (const float*)d_in[4];
    const float* dec_b   = (const float*)d_in[5];
    const float* em_W    = (const float*)d_in[6];
    const float* em_bias = (const float*)d_in[7];
    const float* em_g    = (const float*)d_in[8];
    const float* em_beta = (const float*)d_in[9];
    const float* td_W    = (const float*)d_in[10];
    const float* td_b    = (const float*)d_in[11];
    const float* tm_W    = (const float*)d_in[12];
    const float* tm_bias = (const float*)d_in[13];
    const float* tn_g    = (const float*)d_in[14];
    const float* tn_beta = (const float*)d_in[15];
    float* out = (float*)d_out;

    float* ws     = (float*)d_ws;
    float* P0     = ws;                    // 131584
    float* P1     = P0 + 131584;           // 131584
    float* lse_em = P1 + 131584;           // 256
    float* part   = lse_em + 256;          // 256*196*2 = 100352
    float* lse_t  = part + 100352;         // 66049 (+pad)
    unsigned short* tdw_bf = (unsigned short*)(lse_t + 66052);  // 131072 ushort
    unsigned short* h_bf   = tdw_bf + 131072;                   // 65536 ushort
    unsigned short* E      = h_bf + 65536;                      // 50176*256 = 12845056 ushort (25.7MB)
    unsigned short* Td     = E + (size_t)50176*256;             // 66049*256 = 16908544 ushort (33.8MB)
    // total ~61.6 MB of workspace

    hipMemsetAsync(out, 0, Bb*sizeof(float), stream);
    k_h<<<Kst, 256, 0, stream>>>(lembs, em_W, em_bias, em_g, em_beta, h_bf);
    k_P<<<KP1, 256, 0, stream>>>(tlembs, tm_W, P0, P1);
    k_tdw<<<128, 256, 0, stream>>>(td_W, tdw_bf);
    k_em_mfma<<<dim3(VB2, 4), 256, 0, stream>>>(dec_W, dec_b, h_bf, part, E);
    k_em_comb<<<1, Kst, 0, stream>>>(part, lse_em);
    k_trans2<<<(NROWS + 63)/64, 256, 0, stream>>>(tlembs, P0, P1, tm_bias,
                                                  tn_g, tn_beta, (const short*)tdw_bf,
                                                  td_b, lse_t, Td);
    k_gather2<<<Tt/TCH, 256, 0, stream>>>(x, z, E, lse_em, Td, lse_t, out);
}